// Round 2
// baseline (852.162 us; speedup 1.0000x reference)
//
#include <hip/hip_runtime.h>
#include <hip/hip_bf16.h>

typedef __attribute__((ext_vector_type(4))) float f32x4;
typedef __attribute__((ext_vector_type(8))) short bf16x8;

#define GL2LDS16(g, l) __builtin_amdgcn_global_load_lds(                     \
    (const __attribute__((address_space(1))) void*)(g),                      \
    (__attribute__((address_space(3))) void*)(l), 16, 0, 0)

__device__ __forceinline__ float b2f(unsigned short u) {
  union { unsigned int i; float f; } x;
  x.i = ((unsigned int)u) << 16;
  return x.f;
}
__device__ __forceinline__ unsigned short f2b(float f) {
  __hip_bfloat16 h = __float2bfloat16(f);
  return *reinterpret_cast<unsigned short*>(&h);
}

// ---------------- cvt: x fp32 -> bf16 (vectorized) --------------------------
__global__ __launch_bounds__(256) void cvt_x(
    const float4* __restrict__ x, ushort4* __restrict__ xb, int n4)
{
  for (int i = blockIdx.x * 256 + threadIdx.x; i < n4; i += gridDim.x * 256) {
    float4 v = x[i];
    ushort4 o;
    o.x = f2b(v.x); o.y = f2b(v.y); o.z = f2b(v.z); o.w = f2b(v.w);
    xb[i] = o;
  }
}

// ---------------- prep: transpose weights + pre-swizzle bias ----------------
// biasC layout: [h][mt*6+ct][lane][r] bf16, row=mt*16+quad*4+r, col=ct*16+(lane&15)
// padded key columns (col>=84) get -1e30 so exp() kills them exactly.
__global__ __launch_bounds__(256) void prep_k(
    const float* __restrict__ Wqkv,    // [256][768] fp32
    const float* __restrict__ Wproj,   // [256][256] fp32
    const float* __restrict__ btab,    // [207][8]   fp32
    const int* __restrict__ relidx,    // [84][84]
    __hip_bfloat16* __restrict__ WqkvT,   // [768][256] bf16
    __hip_bfloat16* __restrict__ WprojT,  // [256][256] bf16
    __hip_bfloat16* __restrict__ biasC)   // [8][36][64][4] bf16
{
  int idx = blockIdx.x * 256 + threadIdx.x;
  if (idx < 196608) {
    int n = idx >> 8, k = idx & 255;
    WqkvT[idx] = __float2bfloat16(Wqkv[k * 768 + n]);
  } else if (idx < 262144) {
    int i = idx - 196608;
    int n = i >> 8, k = i & 255;
    WprojT[i] = __float2bfloat16(Wproj[k * 256 + n]);
  } else if (idx < 335872) {
    int i = idx - 262144;
    int r = i & 3, lane = (i >> 2) & 63, tile = i >> 8;
    int ct = tile % 6, mt = (tile / 6) % 6, h = tile / 36;
    int row = mt * 16 + ((lane >> 4) << 2) + r;
    int col = ct * 16 + (lane & 15);
    float v;
    if (col >= 84)      v = -1e30f;   // padded key -> softmax weight 0
    else if (row >= 84) v = 0.0f;     // padded query row -> never stored
    else                v = btab[relidx[row * 84 + col] * 8 + h];
    biasC[i] = __float2bfloat16(v);
  }
}

// ---------------- GEMM: C[M][N] = A[M][256] @ Bt[N][256]^T + bias ----------
// m97 structure: 128x128 block tile, 4 waves of 4x4 16x16 tiles, BK=32,
// global_load_lds width-16 staging (wave-uniform LDS base + lane*16).
// OUTF=1 -> fp32 C, OUTF=0 -> bf16 C.
template <int OUTF>
__global__ __launch_bounds__(256, 2) void gemm_bt(
    const __hip_bfloat16* __restrict__ A,
    const __hip_bfloat16* __restrict__ Bt,
    const float* __restrict__ bias,
    void* __restrict__ Cv,
    const int N)
{
  __shared__ __align__(16) __hip_bfloat16 As[128 * 32];
  __shared__ __align__(16) __hip_bfloat16 Bs[128 * 32];
  const int t = threadIdx.x;
  const int w = t >> 6, lane = t & 63;
  const int lane15 = lane & 15, quad = lane >> 4;
  const int m0 = blockIdx.x * 128, n0 = blockIdx.y * 128;
  const int wm = (w >> 1) * 64, wn = (w & 1) * 64;
  const int srow = w * 16 + (lane >> 2);   // staged row within 64-row half
  const int scol = (lane & 3) * 8;         // element offset within 32-wide K slab
  const __hip_bfloat16* gA = A + (size_t)(m0 + srow) * 256 + scol;
  const __hip_bfloat16* gB = Bt + (size_t)(n0 + srow) * 256 + scol;
  __hip_bfloat16* lA = As + w * 16 * 32;   // wave-uniform LDS base
  __hip_bfloat16* lB = Bs + w * 16 * 32;
  f32x4 acc[4][4] = {};
#pragma unroll 1
  for (int kk = 0; kk < 8; ++kk) {
    GL2LDS16(gA + kk * 32, lA);
    GL2LDS16(gA + 64 * 256 + kk * 32, lA + 64 * 32);
    GL2LDS16(gB + kk * 32, lB);
    GL2LDS16(gB + 64 * 256 + kk * 32, lB + 64 * 32);
    __syncthreads();  // compiler inserts vmcnt(0) drain before barrier
    bf16x8 af[4], bfr[4];
#pragma unroll
    for (int i = 0; i < 4; ++i)
      af[i] = *(const bf16x8*)(As + (wm + i * 16 + lane15) * 32 + quad * 8);
#pragma unroll
    for (int j = 0; j < 4; ++j)
      bfr[j] = *(const bf16x8*)(Bs + (wn + j * 16 + lane15) * 32 + quad * 8);
#pragma unroll
    for (int i = 0; i < 4; ++i)
#pragma unroll
      for (int j = 0; j < 4; ++j)
        acc[i][j] = __builtin_amdgcn_mfma_f32_16x16x32_bf16(af[i], bfr[j], acc[i][j], 0, 0, 0);
    __syncthreads();
  }
#pragma unroll
  for (int j = 0; j < 4; ++j) {
    const int col = n0 + wn + j * 16 + lane15;
    const float bv = bias[col];
#pragma unroll
    for (int i = 0; i < 4; ++i) {
      const int row = m0 + wm + i * 16 + quad * 4;
#pragma unroll
      for (int r = 0; r < 4; ++r) {
        const size_t o = (size_t)(row + r) * N + col;
        if (OUTF) ((float*)Cv)[o] = acc[i][j][r] + bv;
        else ((__hip_bfloat16*)Cv)[o] = __float2bfloat16(acc[i][j][r] + bv);
      }
    }
  }
}

// ---------------- fused attention (softmax(QK^T*s + bias) @ V) -------------
// 1 block per batch element; wave w handles heads w and w+4. All LDS per-wave
// => no __syncthreads. Tokens padded 84->96; padded key cols killed by -1e30
// bias; padded query rows computed but never stored (rowmax includes own row
// so exp<=1 everywhere, no Inf/NaN).
__global__ __launch_bounds__(256, 1) void attn_k(
    const __hip_bfloat16* __restrict__ qkv,    // [172048][768] (pad rows for last-batch frag reads)
    const __hip_bfloat16* __restrict__ biasC,  // [8][36][64][4]
    __hip_bfloat16* __restrict__ aout)         // [172032][256]
{
  __shared__ __align__(16) __hip_bfloat16 Pb[4][96 * 104];
  __shared__ __align__(16) __hip_bfloat16 Vt[4][32 * 104];
  const int b = blockIdx.x;
  const int t = threadIdx.x;
  const int w = t >> 6, lane = t & 63;
  const int lane15 = lane & 15, quad = lane >> 4;
  const __hip_bfloat16* base = qkv + (size_t)b * (84 * 768);
  __hip_bfloat16* Pw = Pb[w];
  __hip_bfloat16* Vw = Vt[w];
  const float scale = 0.10910894511799619f;  // 84^-0.5

  // zero V^T pad columns (key tokens 84..95): P=0 there, but 0*garbage traps us
  for (int i = lane; i < 32 * 12; i += 64) {
    int d = i / 12, tok = 84 + (i % 12);
    Vw[d * 104 + tok] = __float2bfloat16(0.0f);
  }

  for (int hi = 0; hi < 2; ++hi) {
    const int h = w + 4 * hi;
    // stage V^T: Vw[d][tok] = V[tok][d]
    for (int i = lane; i < 84 * 32; i += 64) {
      int tok = i >> 5, d = i & 31;
      Vw[d * 104 + tok] = base[(size_t)tok * 768 + 512 + h * 32 + d];
    }
    // Q.K^T : A/B fragments are contiguous 16B chunks straight from global
    bf16x8 qa[6], kb[6];
#pragma unroll
    for (int i = 0; i < 6; ++i)
      qa[i] = *(const bf16x8*)(base + (size_t)(i * 16 + lane15) * 768 + h * 32 + quad * 8);
#pragma unroll
    for (int j = 0; j < 6; ++j)
      kb[j] = *(const bf16x8*)(base + (size_t)(j * 16 + lane15) * 768 + 256 + h * 32 + quad * 8);
    f32x4 S[6][6] = {};
#pragma unroll
    for (int i = 0; i < 6; ++i)
#pragma unroll
      for (int j = 0; j < 6; ++j)
        S[i][j] = __builtin_amdgcn_mfma_f32_16x16x32_bf16(qa[i], kb[j], S[i][j], 0, 0, 0);

    // softmax: a row of S spans the 16 lanes of a quad-group (col=lane&15)
    const unsigned short* bC = (const unsigned short*)biasC + (size_t)h * 9216 + lane * 4;
    f32x4 inv[6];
#pragma unroll
    for (int mt = 0; mt < 6; ++mt) {
      f32x4 mx = {-3.0e38f, -3.0e38f, -3.0e38f, -3.0e38f};
#pragma unroll
      for (int ct = 0; ct < 6; ++ct) {
        ushort4 bb = *(const ushort4*)(bC + (mt * 6 + ct) * 256);
        f32x4 tv;
        tv[0] = S[mt][ct][0] * scale + b2f(bb.x);
        tv[1] = S[mt][ct][1] * scale + b2f(bb.y);
        tv[2] = S[mt][ct][2] * scale + b2f(bb.z);
        tv[3] = S[mt][ct][3] * scale + b2f(bb.w);
        S[mt][ct] = tv;
        mx[0] = fmaxf(mx[0], tv[0]); mx[1] = fmaxf(mx[1], tv[1]);
        mx[2] = fmaxf(mx[2], tv[2]); mx[3] = fmaxf(mx[3], tv[3]);
      }
#pragma unroll
      for (int off = 1; off < 16; off <<= 1) {
#pragma unroll
        for (int r = 0; r < 4; ++r)
          mx[r] = fmaxf(mx[r], __shfl_xor(mx[r], off, 64));
      }
      f32x4 sm = {0.f, 0.f, 0.f, 0.f};
#pragma unroll
      for (int ct = 0; ct < 6; ++ct) {
#pragma unroll
        for (int r = 0; r < 4; ++r) {
          float p = __expf(S[mt][ct][r] - mx[r]);
          sm[r] += p;
          // C-layout -> row-major P~ in per-wave LDS (A-operand for PV)
          Pw[(mt * 16 + quad * 4 + r) * 104 + ct * 16 + lane15] = __float2bfloat16(p);
        }
      }
#pragma unroll
      for (int off = 1; off < 16; off <<= 1) {
#pragma unroll
        for (int r = 0; r < 4; ++r)
          sm[r] += __shfl_xor(sm[r], off, 64);
      }
      inv[mt][0] = 1.0f / sm[0]; inv[mt][1] = 1.0f / sm[1];
      inv[mt][2] = 1.0f / sm[2]; inv[mt][3] = 1.0f / sm[3];
    }

    // P~ @ V  (K = 96 over 3 slabs of 32)
    f32x4 O[6][2] = {};
#pragma unroll
    for (int kk = 0; kk < 3; ++kk) {
      bf16x8 vb0 = *(const bf16x8*)(Vw + lane15 * 104 + kk * 32 + quad * 8);
      bf16x8 vb1 = *(const bf16x8*)(Vw + (16 + lane15) * 104 + kk * 32 + quad * 8);
#pragma unroll
      for (int mt = 0; mt < 6; ++mt) {
        bf16x8 pa = *(const bf16x8*)(Pw + (mt * 16 + lane15) * 104 + kk * 32 + quad * 8);
        O[mt][0] = __builtin_amdgcn_mfma_f32_16x16x32_bf16(pa, vb0, O[mt][0], 0, 0, 0);
        O[mt][1] = __builtin_amdgcn_mfma_f32_16x16x32_bf16(pa, vb1, O[mt][1], 0, 0, 0);
      }
    }
    // normalize + store rows < 84
#pragma unroll
    for (int mt = 0; mt < 6; ++mt) {
#pragma unroll
      for (int r = 0; r < 4; ++r) {
        int row = mt * 16 + quad * 4 + r;
        if (row < 84) {
          size_t o = (size_t)(b * 84 + row) * 256 + h * 32 + lane15;
          aout[o]      = __float2bfloat16(O[mt][0][r] * inv[mt][r]);
          aout[o + 16] = __float2bfloat16(O[mt][1][r] * inv[mt][r]);
        }
      }
    }
  }
}

// ---------------------------------------------------------------------------
extern "C" void kernel_launch(void* const* d_in, const int* in_sizes, int n_in,
                              void* d_out, int out_size, void* d_ws, size_t ws_size,
                              hipStream_t stream) {
  const float* x     = (const float*)d_in[0];
  const float* Wqkv  = (const float*)d_in[1];
  const float* bqkv  = (const float*)d_in[2];
  const float* Wproj = (const float*)d_in[3];
  const float* bproj = (const float*)d_in[4];
  const float* btab  = (const float*)d_in[5];
  const int* relidx  = (const int*)d_in[6];
  float* out = (float*)d_out;

  char* ws = (char*)d_ws;
  const size_t QKV_BYTES  = (size_t)172048 * 768 * 2;   // 264,265,728 (pad rows)
  const size_t REG2_BYTES = (size_t)172032 * 256 * 2;   //  88,080,384 (xb then aout)
  const size_t SMALL_BYTES = (size_t)(768 * 256 + 256 * 256 + 73728) * 2;
  if (ws_size < QKV_BYTES + REG2_BYTES + SMALL_BYTES) return;  // 353,017,856 B

  __hip_bfloat16* qkv  = (__hip_bfloat16*)ws;
  __hip_bfloat16* reg2 = (__hip_bfloat16*)(ws + QKV_BYTES);   // xb during GEMM-1, aout after
  __hip_bfloat16* WqkvT  = (__hip_bfloat16*)(ws + QKV_BYTES + REG2_BYTES);
  __hip_bfloat16* WprojT = WqkvT + 768 * 256;
  __hip_bfloat16* biasC  = WprojT + 256 * 256;

  cvt_x<<<1024, 256, 0, stream>>>((const float4*)x, (ushort4*)reg2, 172032 * 256 / 4);
  prep_k<<<1312, 256, 0, stream>>>(Wqkv, Wproj, btab, relidx, WqkvT, WprojT, biasC);
  gemm_bt<0><<<dim3(1344, 6), 256, 0, stream>>>(reg2, WqkvT, bqkv, qkv, 768);
  attn_k<<<2048, 256, 0, stream>>>(qkv, biasC, reg2);
  gemm_bt<1><<<dim3(1344, 2), 256, 0, stream>>>(reg2, WprojT, bproj, out, 256);
}